// Round 11
// baseline (451.089 us; speedup 1.0000x reference)
//
#include <hip/hip_runtime.h>
#include <cstdint>
#include <cstddef>

#define B_   8
#define LQ_  2048
#define LK_  2048

typedef __attribute__((ext_vector_type(8))) __bf16 bf16x8;
typedef __attribute__((ext_vector_type(4))) float f32x4;
typedef __attribute__((ext_vector_type(8))) unsigned short ushortx8;

__device__ __forceinline__ unsigned short f2bf(float f) {
  unsigned u = __builtin_bit_cast(unsigned, f);
  u = u + 0x7fffu + ((u >> 16) & 1u);  // round-to-nearest-even
  return (unsigned short)(u >> 16);
}
__device__ __forceinline__ float bf2f(unsigned short h) {
  unsigned u = ((unsigned)h) << 16;
  return __builtin_bit_cast(float, u);
}

__device__ __forceinline__ void gld_lds16(const void* g, void* l) {
  __builtin_amdgcn_global_load_lds((__attribute__((address_space(1))) void*)(void*)g,
                                   (__attribute__((address_space(3))) void*)l, 16, 0, 0);
}

// ====== 256x128 GEMM: 4 waves, per-wave 128x64, BK=32, ring-2 (48 KB) ======
// K-loop schedule = r9 verbatim (proven: 71.6 us GEMM2, 0 bank conflicts, VGPR 92).
// New this round (r11):
//  STGF32: stage A,B from FP32 globals via reg-staging (load f32x8 -> cvt bf16 ->
//    ds_write_b128 to the SAME XOR-swizzled layout). Used by GEMM1' so keys/W need
//    no pre-cast dispatch (keys read once). __syncthreads per K-tile (drains lgkm
//    so ds_writes are visible cross-wave; replaces vmcnt fence of the gld path).
//  SPLITK: grid gains an sk bit. Batches with round64(vl) >= 1024 split the K-range
//    in half; both halves atomically add fp32 into C (out pre-zeroed by the softmax
//    launch's backfill). Short batches: sk=0 full-K plain store, sk=1 exits.
//    Halves the GEMM3 pole block (64 -> 32 K-tiles).
//  AUX (GEMM1' launch): blocks [ngemm, ngemm+8192) = queries fp32->bf16 cast;
//    blocks [ngemm+8192, ...) = V-transpose tiles (valsT[b][v][s] = values[b][s][v],
//    s-rows clamped to round64(vl)). Both independent of the GEMM math; they
//    backfill the ~224 culled GEMM slots.
// Hazards (unchanged from refcheck-proven r9): stage(t+1) targets slot of tile
// t-1, whose frag-reads completed before iter-(t-1)'s sync; end-of-iter fence
// (vmcnt(0) asm / __syncthreads) proves residency of tile t+1.
// LDS layout: rowpair [*/2][64]; 16B-chunk XOR swizzle pos = c ^ (p&7).
// OUTM: 0 bf16, 1 bf16*scale, 2 fp32. SKIPN/SKIPM: cull n0/m0 >= vl.
// CLAMPK: clamp K-loop to round64(vl).
template <int OUTM, int SKIPN, int SKIPM, int CLAMPK, int AUX, int STGF32, int SPLITK>
__global__ __launch_bounds__(256, 2) void gemm256x128_kernel(
    const unsigned short* __restrict__ A, const unsigned short* __restrict__ B,
    void* __restrict__ Cp, int M, int N, int K,
    long a_bstride, long b_bstride, long c_bstride, float scale,
    const int* __restrict__ vlp, int lognx,
    const float* __restrict__ auxf, unsigned short* __restrict__ auxo,
    const float* __restrict__ auxf2, unsigned short* __restrict__ auxo2,
    int ngemm) {
  __shared__ unsigned short lds[2][128 * 64 + 64 * 64];  // [ring][A:8192 | B:4096]

  const int tid = threadIdx.x;

  if constexpr (AUX) {
    const int bi = (int)blockIdx.x - ngemm;
    if (bi >= 0) {
      if (bi < 8192) {  // ---- queries fp32->bf16 cast backfill ----
        size_t i = ((size_t)bi * 256 + tid) * 8;
        float4 a = *(const float4*)(auxf + i);
        float4 b = *(const float4*)(auxf + i + 4);
        ushortx8 o;
        o[0] = f2bf(a.x); o[1] = f2bf(a.y); o[2] = f2bf(a.z); o[3] = f2bf(a.w);
        o[4] = f2bf(b.x); o[5] = f2bf(b.y); o[6] = f2bf(b.z); o[7] = f2bf(b.w);
        *(ushortx8*)(auxo + i) = o;
      } else {  // ---- V-transpose backfill: 8x 32x32 tiles per block ----
        float* smem = (float*)&lds[0][0];  // 32x33 fp32 overlay
        const int vb = bi - 8192;          // [0, 2048)
        const int tx = tid & 31, ty = tid >> 5;  // (32,8)
#pragma unroll 1
        for (int u = 0; u < 8; ++u) {
          const int t = vb * 8 + u;  // tile id: z*2048 + ry*32 + cx
          const int z = t >> 11;
          const int r0 = ((t >> 5) & 63) * 32;   // s-rows (vl-clamped)
          const int c0 = (t & 31) * 32;          // v-cols
          const int ke = (vlp[z] + 63) & ~63;    // GEMM3 CLAMPK read range
          if (r0 < ke) {                          // block-uniform branch
            const float* inb = auxf2 + (size_t)z * 2048 * 1024;
            unsigned short* outb = auxo2 + (size_t)z * 1024 * 2048;
#pragma unroll
            for (int k = 0; k < 4; ++k) {
              int r = ty + k * 8;
              smem[r * 33 + tx] = inb[(size_t)(r0 + r) * 1024 + c0 + tx];
            }
            __syncthreads();
#pragma unroll
            for (int k = 0; k < 4; ++k) {
              int c = ty + k * 8;
              outb[(size_t)(c0 + c) * 2048 + r0 + tx] = f2bf(smem[tx * 33 + c]);
            }
            __syncthreads();
          }
        }
      }
      return;
    }
  }

  const int wid = tid >> 6;
  const int lane = tid & 63;
  const int lane15 = lane & 15;
  const int lhalf = lane >> 4;

  // ---- 1-D grid decode: z inner, then (optional) sk, then x, y ----
  const int idx = (int)blockIdx.x;
  const int z = idx & 7;
  int rest = idx >> 3;
  int sk = 0;
  if constexpr (SPLITK) {
    sk = rest & 1;
    rest >>= 1;
  }
  const int nxm = (1 << lognx) - 1;
  const int xt = rest & nxm;
  const int yt = rest >> lognx;
  const int nt = (xt + 2 * z) & nxm;  // batch-rotated n-tile
  const int m0 = yt * 256;
  const int n0 = nt * 128;

  int vl = K;
  if constexpr (SKIPN || SKIPM || CLAMPK) vl = vlp[z];
  if constexpr (SKIPN) {
    if (n0 >= vl) return;
  }
  if constexpr (SKIPM) {
    if (m0 >= vl) return;
  }
  int kEnd = K;
  if constexpr (CLAMPK) {
    int ke = (vl + 63) & ~63;
    kEnd = ke < K ? ke : K;
  }
  const int nKt = kEnd >> 5;  // K-tiles of 32; even, >= 2

  int t0 = 0, t1 = nKt;
  bool split = false;
  if constexpr (SPLITK) {
    if (nKt >= 32) {  // split only long-K batches; nKt even -> equal halves
      split = true;
      const int h = nKt >> 1;
      if (sk) t0 = h; else t1 = h;
    } else if (sk) {
      return;  // short batch: sk=0 does full K with plain stores
    }
  }

  // ---- staging precompute: A 1024 chunks (4/thr), B 512 chunks (2/thr) ----
  // chunk blk: p=blk>>3 (rowpair), c=(blk&7)^(p&7): src row=2p+(c>>2),
  // src col=(c&3)*8, LDS dst=blk*16B (within operand region).
  int srA[4], scA[4], sdA[4];
#pragma unroll
  for (int j = 0; j < 4; ++j) {
    int blk = (wid * 4 + j) * 64 + lane;  // wave-uniform base + lane (gld_lds req)
    int p = blk >> 3;
    int c = (blk & 7) ^ (p & 7);
    srA[j] = m0 + 2 * p + (c >> 2);
    scA[j] = (c & 3) * 8;
    sdA[j] = blk * 8;
  }
  int srB[2], scB[2], sdB[2];
#pragma unroll
  for (int j = 0; j < 2; ++j) {
    int blk = (wid * 2 + j) * 64 + lane;
    int p = blk >> 3;
    int c = (blk & 7) ^ (p & 7);
    srB[j] = n0 + 2 * p + (c >> 2);
    scB[j] = (c & 3) * 8;
    sdB[j] = 8192 + blk * 8;
  }

  // ---- read precompute (wave 2M x 2N -> 128x64 each) ----
  const int om = (wid & 1) * 128;  // wave M origin in tile
  const int on = (wid >> 1) * 64;  // wave N origin in tile
  const int swz8 = ((((lane15 & 1) << 2) + lhalf) ^ ((lane15 >> 1) & 7)) << 3;
  const int aBase = ((om >> 1) + (lane15 >> 1)) * 64 + swz8;
  const int bBase = 8192 + ((on >> 1) + (lane15 >> 1)) * 64 + swz8;

  f32x4 acc[8][4];
#pragma unroll
  for (int f = 0; f < 8; ++f)
#pragma unroll
    for (int g = 0; g < 4; ++g) acc[f][g] = (f32x4){0.f, 0.f, 0.f, 0.f};

  if constexpr (STGF32) {
    // ======== FP32-source reg-staged path (GEMM1': keys + W direct) ========
    const float* Af = (const float*)(const void*)A + (size_t)z * a_bstride;
    const float* Bf = (const float*)(const void*)B + (size_t)z * b_bstride;
    float4 pa[4][2], pb[2][2];

#define LOADF(T)                                                                \
  {                                                                             \
    const int kc_ = (T) * 32;                                                   \
    _Pragma("unroll")                                                           \
    for (int j = 0; j < 4; ++j) {                                               \
      const float* s = Af + (size_t)srA[j] * K + (kc_ + scA[j]);                \
      pa[j][0] = *(const float4*)s;                                             \
      pa[j][1] = *(const float4*)(s + 4);                                       \
    }                                                                           \
    _Pragma("unroll")                                                           \
    for (int j = 0; j < 2; ++j) {                                               \
      const float* s = Bf + (size_t)srB[j] * K + (kc_ + scB[j]);                \
      pb[j][0] = *(const float4*)s;                                             \
      pb[j][1] = *(const float4*)(s + 4);                                       \
    }                                                                           \
  }
#define WRITEF(S)                                                               \
  {                                                                             \
    _Pragma("unroll")                                                           \
    for (int j = 0; j < 4; ++j) {                                               \
      ushortx8 o;                                                               \
      o[0] = f2bf(pa[j][0].x); o[1] = f2bf(pa[j][0].y);                         \
      o[2] = f2bf(pa[j][0].z); o[3] = f2bf(pa[j][0].w);                         \
      o[4] = f2bf(pa[j][1].x); o[5] = f2bf(pa[j][1].y);                         \
      o[6] = f2bf(pa[j][1].z); o[7] = f2bf(pa[j][1].w);                         \
      *(ushortx8*)&lds[S][sdA[j]] = o;                                          \
    }                                                                           \
    _Pragma("unroll")                                                           \
    for (int j = 0; j < 2; ++j) {                                               \
      ushortx8 o;                                                               \
      o[0] = f2bf(pb[j][0].x); o[1] = f2bf(pb[j][0].y);                         \
      o[2] = f2bf(pb[j][0].z); o[3] = f2bf(pb[j][0].w);                         \
      o[4] = f2bf(pb[j][1].x); o[5] = f2bf(pb[j][1].y);                         \
      o[6] = f2bf(pb[j][1].z); o[7] = f2bf(pb[j][1].w);                         \
      *(ushortx8*)&lds[S][sdB[j]] = o;                                          \
    }                                                                           \
  }

    LOADF(t0);
    WRITEF(0);
    __syncthreads();
    for (int t = t0; t < t1; ++t) {
      const int cur = (t - t0) & 1;
      const unsigned short* lcur = &lds[cur][0];
      if (t + 1 < t1) LOADF(t + 1);  // loads land under MFMA phase

      bf16x8 a[8], b[4];
#pragma unroll
      for (int f = 0; f < 8; ++f) a[f] = *(const bf16x8*)&lcur[aBase + f * 512];
#pragma unroll
      for (int g = 0; g < 4; ++g) b[g] = *(const bf16x8*)&lcur[bBase + g * 512];
#pragma unroll
      for (int f = 0; f < 8; ++f)
#pragma unroll
        for (int g = 0; g < 4; ++g)
          acc[f][g] = __builtin_amdgcn_mfma_f32_16x16x32_bf16(a[f], b[g], acc[f][g], 0, 0, 0);

      if (t + 1 < t1) WRITEF(cur ^ 1);  // overwrites slot of tile t-1 (reads done)
      __syncthreads();                  // lgkm drain: writes visible to all waves
    }
#undef LOADF
#undef WRITEF
  } else {
    // ======== bf16-source global_load_lds path (GEMM2 / GEMM3) ========
    const unsigned short* Ab = A + (size_t)z * a_bstride;
    const unsigned short* Bb = B + (size_t)z * b_bstride;

#define STAGE_TILE(T, S)                                                        \
  {                                                                             \
    const int kc_ = (T) * 32;                                                   \
    _Pragma("unroll")                                                           \
    for (int j = 0; j < 4; ++j)                                                 \
      gld_lds16(Ab + (size_t)srA[j] * K + (kc_ + scA[j]), &lds[S][sdA[j]]);     \
    _Pragma("unroll")                                                           \
    for (int j = 0; j < 2; ++j)                                                 \
      gld_lds16(Bb + (size_t)srB[j] * K + (kc_ + scB[j]), &lds[S][sdB[j]]);     \
  }

    STAGE_TILE(t0, 0);
    asm volatile("s_waitcnt vmcnt(0)" ::: "memory");
    __builtin_amdgcn_s_barrier();

    for (int t = t0; t < t1; ++t) {
      const int cur = (t - t0) & 1;
      const unsigned short* lcur = &lds[cur][0];
      if (t + 1 < t1) STAGE_TILE(t + 1, cur ^ 1);

      bf16x8 a[8], b[4];
#pragma unroll
      for (int f = 0; f < 8; ++f) a[f] = *(const bf16x8*)&lcur[aBase + f * 512];
#pragma unroll
      for (int g = 0; g < 4; ++g) b[g] = *(const bf16x8*)&lcur[bBase + g * 512];
      // UNPINNED: compiler emits fine-grained lgkmcnt between reads and MFMAs.
#pragma unroll
      for (int f = 0; f < 8; ++f)
#pragma unroll
        for (int g = 0; g < 4; ++g)
          acc[f][g] = __builtin_amdgcn_mfma_f32_16x16x32_bf16(a[f], b[g], acc[f][g], 0, 0, 0);
      asm volatile("s_waitcnt vmcnt(0)" ::: "memory");  // next tile resident
      __builtin_amdgcn_s_barrier();
    }
#undef STAGE_TILE
  }

  // ---- epilogue: C/D layout col=lane&15, row=(lane>>4)*4+reg ----
  const size_t boffC = (size_t)z * c_bstride;
#pragma unroll
  for (int f = 0; f < 8; ++f) {
    int row = m0 + om + f * 16 + lhalf * 4;
#pragma unroll
    for (int g = 0; g < 4; ++g) {
      int col = n0 + on + g * 16 + lane15;
#pragma unroll
      for (int r = 0; r < 4; ++r) {
        float v = acc[f][g][r];
        if constexpr (OUTM == 0) {
          ((unsigned short*)Cp + boffC)[(size_t)(row + r) * N + col] = f2bf(v);
        } else if constexpr (OUTM == 1) {
          ((unsigned short*)Cp + boffC)[(size_t)(row + r) * N + col] = f2bf(v * scale);
        } else {
          float* op = (float*)Cp + boffC;
          if constexpr (SPLITK) {
            if (split) {
              __hip_atomic_fetch_add(&op[(size_t)(row + r) * N + col], v,
                                     __ATOMIC_RELAXED, __HIP_MEMORY_SCOPE_AGENT);
              continue;
            }
          }
          op[(size_t)(row + r) * N + col] = v;
        }
      }
    }
  }
}

// ========== softmax + zero-init backfill ==========
// blocks [0,16384): row softmax with valid_len masking, in place on bf16 scores;
//   cols [vl, round64(vl)) get exact 0 (GEMM3 CLAMPK read range).
// blocks [16384,18432): zero-init `out` for split-K batches (round64(vl) >= 1024);
//   GEMM3's two K-halves then atomic-add into it. Runs before GEMM3 (stream order).
__global__ __launch_bounds__(256) void softmax_zero_kernel(
    unsigned short* __restrict__ scores, const int* __restrict__ valid_lens,
    float* __restrict__ out) {
  const int bb = (int)blockIdx.x;
  const int tid = threadIdx.x;

  if (bb >= 16384) {
    const int zb = bb - 16384;  // [0, 2048): 256 blocks x 32 KB per batch
    const int z = zb >> 8;
    if (((valid_lens[z] + 63) & ~63) >= 1024) {
      float* p = out + ((size_t)z << 21) + ((size_t)(zb & 255) << 13) + tid * 32;
      const f32x4 zer = {0.f, 0.f, 0.f, 0.f};
#pragma unroll
      for (int u = 0; u < 8; ++u) *(f32x4*)(p + u * 4) = zer;
    }
    return;
  }

  const int row = bb;
  const int b = row >> 11;  // LQ = 2048
  const int vl = valid_lens[b];
  const int kEnd = (vl + 63) & ~63;
  unsigned short* rp = scores + (size_t)row * LK_;
  const int wid = tid >> 6, lane = tid & 63;
  __shared__ float sred[4];

  const int cb = tid * 8;
  const bool act = cb < kEnd;
  ushortx8 h = {};
  if (act) h = *(const ushortx8*)(rp + cb);
  float x[8];
#pragma unroll
  for (int t = 0; t < 8; ++t) x[t] = bf2f(h[t]);

  float m = -3.4e38f;
#pragma unroll
  for (int t = 0; t < 8; ++t)
    if (cb + t < vl) m = fmaxf(m, x[t]);
#pragma unroll
  for (int off = 32; off >= 1; off >>= 1) m = fmaxf(m, __shfl_xor(m, off));
  if (lane == 0) sred[wid] = m;
  __syncthreads();
  m = fmaxf(fmaxf(sred[0], sred[1]), fmaxf(sred[2], sred[3]));
  __syncthreads();

  float e[8];
  float s = 0.f;
#pragma unroll
  for (int t = 0; t < 8; ++t) {
    e[t] = (cb + t < vl) ? __expf(x[t] - m) : 0.f;
    s += e[t];
  }
#pragma unroll
  for (int off = 32; off >= 1; off >>= 1) s += __shfl_xor(s, off);
  if (lane == 0) sred[wid] = s;
  __syncthreads();
  s = sred[0] + sred[1] + sred[2] + sred[3];
  float inv = 1.f / s;

  if (act) {
    ushortx8 o;
#pragma unroll
    for (int t = 0; t < 8; ++t) o[t] = f2bf(e[t] * inv);
    *(ushortx8*)(rp + cb) = o;
  }
}

extern "C" void kernel_launch(void* const* d_in, const int* in_sizes, int n_in,
                              void* d_out, int out_size, void* d_ws, size_t ws_size,
                              hipStream_t stream) {
  const float* queries = (const float*)d_in[0];    // [8,2048,1024]
  const float* keys = (const float*)d_in[1];       // [8,2048,1024]
  const float* values = (const float*)d_in[2];     // [8,2048,1024]
  const int* valid_lens = (const int*)d_in[3];     // [8]
  const float* W_q = (const float*)d_in[4];        // [1024,1024]
  float* out = (float*)d_out;                      // [8,2048,1024] fp32

  // Re-association: scores = Q @ (K @ W^T)^T — project KEYS (maskable).
  // ws layout (ushort elems), total 80M = 160 MiB:
  //   q_bf    [0, 16M)      queries bf16 (written by GEMM1' backfill)
  //   scores  [16M, 48M)
  //   keysP   [48M, 64M)    K@W^T bf16
  //   valsT   [64M, 80M)    V^T bf16 (written by GEMM1' backfill)
  unsigned short* ws = (unsigned short*)d_ws;
  const size_t M1 = (size_t)1024 * 1024;
  unsigned short* q_bf = ws;
  unsigned short* scores = ws + 16 * M1;
  unsigned short* keysP = ws + 48 * M1;
  unsigned short* valsT = ws + 64 * M1;

  // GEMM1': keysP[b] = keys[b] @ W_q^T (both FP32-staged in-kernel — no cast
  // dispatch; keys read exactly once). Blocks [0,512): GEMM (8y x 8x x 8z,
  // z-inner; ~288 alive, m-tiles >= vl culled). Backfill: [512, 8704) queries
  // cast, [8704, 10752) V-transpose (s-rows clamped to round64(vl)).
  gemm256x128_kernel<0, 0, 1, 0, 1, 1, 0><<<dim3(512 + 8192 + 2048), 256, 0, stream>>>(
      (const unsigned short*)(const void*)keys, (const unsigned short*)(const void*)W_q,
      keysP, 2048, 1024, 1024,
      (long)2048 * 1024, 0, (long)2048 * 1024, 1.f, valid_lens, 3,
      queries, q_bf, values, valsT, 512);
  // GEMM2': scores = q_bf @ keysP^T / 32 -> bf16; cull masked n-tiles.
  // grid: 8y x 16x x 8z, z-inner; ~544 alive.
  gemm256x128_kernel<1, 1, 0, 0, 0, 0, 0><<<dim3(8 * 16 * 8), 256, 0, stream>>>(
      q_bf, keysP, scores, 2048, 2048, 1024,
      (long)2048 * 1024, (long)2048 * 1024, (long)2048 * 2048, 0.03125f, valid_lens, 4,
      nullptr, nullptr, nullptr, nullptr, 0);
  // softmax rows (masked, in place) + zero-init of out for split-K batches.
  softmax_zero_kernel<<<dim3(16384 + 2048), 256, 0, stream>>>(scores, valid_lens, out);
  // GEMM3: out = attn @ values (fp32); K clamped to round64(vl); split-K=2 for
  // long batches (atomic-add halves -> pole block 64 -> 32 K-tiles).
  // grid: 8y x 8x x 2sk x 8z (z inner, then sk), 1024 blocks.
  gemm256x128_kernel<2, 0, 0, 1, 0, 0, 1><<<dim3(8 * 8 * 2 * 8), 256, 0, stream>>>(
      scores, valsT, out, 2048, 1024, 2048,
      (long)2048 * 2048, (long)1024 * 2048, (long)2048 * 1024, 1.f, valid_lens, 3,
      nullptr, nullptr, nullptr, nullptr, 0);
}

// Round 12
// 403.905 us; speedup vs baseline: 1.1168x; 1.1168x over previous
//
#include <hip/hip_runtime.h>
#include <cstdint>
#include <cstddef>

#define B_   8
#define LQ_  2048
#define LK_  2048

typedef __attribute__((ext_vector_type(8))) __bf16 bf16x8;
typedef __attribute__((ext_vector_type(4))) float f32x4;
typedef __attribute__((ext_vector_type(8))) unsigned short ushortx8;

__device__ __forceinline__ unsigned short f2bf(float f) {
  unsigned u = __builtin_bit_cast(unsigned, f);
  u = u + 0x7fffu + ((u >> 16) & 1u);  // round-to-nearest-even
  return (unsigned short)(u >> 16);
}
__device__ __forceinline__ float bf2f(unsigned short h) {
  unsigned u = ((unsigned)h) << 16;
  return __builtin_bit_cast(float, u);
}

__device__ __forceinline__ void gld_lds16(const void* g, void* l) {
  __builtin_amdgcn_global_load_lds((__attribute__((address_space(1))) void*)(void*)g,
                                   (__attribute__((address_space(3))) void*)l, 16, 0, 0);
}

// ------------- cast fp32 -> bf16: keys (row-clamped) + W_q only -------------
__global__ __launch_bounds__(256) void cast_kw_kernel(
    const float* __restrict__ k, unsigned short* __restrict__ ko,
    const float* __restrict__ w, unsigned short* __restrict__ wo,
    const int* __restrict__ vlp) {
  int bb = (int)blockIdx.x;
  const float* in;
  unsigned short* out;
  if (bb < 8192) {
    in = k; out = ko;
    int batch = bb >> 10;            // 1024 blocks per batch (2048x1024 elems)
    int row = (bb & 1023) * 2;       // 2 rows per block
    int vl = vlp[batch];
    if (row >= ((vl + 255) & ~255)) return;   // GEMM1' m-grain is 256
  } else {
    bb -= 8192;
    in = w; out = wo;
  }
  size_t i = ((size_t)bb * 256 + threadIdx.x) * 8;
  float4 a = *(const float4*)(in + i);
  float4 b = *(const float4*)(in + i + 4);
  ushortx8 o;
  o[0] = f2bf(a.x); o[1] = f2bf(a.y); o[2] = f2bf(a.z); o[3] = f2bf(a.w);
  o[4] = f2bf(b.x); o[5] = f2bf(b.y); o[6] = f2bf(b.z); o[7] = f2bf(b.w);
  *(ushortx8*)(out + i) = o;
}

// ====== 256x128 GEMM: 4 waves, per-wave 128x64, BK=32, ring-2 (48 KB) ======
// r9 GEMM verbatim (proven: 71.6 us, 0 bank conflicts, VGPR 92) + r11's
// correctness-proven SPLITK option (used by GEMM3 only):
//  SPLITK: grid gains an sk bit. Batches with round64(vl) >= 1024 (nKt >= 32)
//    split the K-range in half; both halves atomic-add fp32 into C (out
//    pre-zeroed by the vtrans_softmax launch's region-3 blocks, stream-ordered).
//    Short batches: sk=0 full-K plain store, sk=1 exits. Halves the GEMM3 pole
//    block (vl=2048: 64 -> 32 K-tiles, the single-block serial floor).
//  AUX=1 (GEMM1' launch only): blocks >= ngemm do queries fp32->bf16 cast
//    (small backfill — ~8192 blocks; r11 showed BULK memory work must not live
//    in a 48KB-LDS launch, but this exact 512+8192 config measured 366 in r9).
// Hazards (refcheck-proven r9): stage(t+1) at loop top targets slot of tile
// t-1 (reads done before iter-(t-1) barrier); end-of-iter vmcnt(0)+barrier
// proves residency; compiler emits fine-grained lgkmcnt for ds_read->MFMA.
// LDS layout: rowpair [*/2][64], 16B-chunk XOR swizzle pos = c ^ (p&7).
// OUTM: 0 bf16, 1 bf16*scale, 2 fp32. SKIPN/SKIPM: cull n0/m0 >= vl.
// CLAMPK: clamp K-loop to round64(vl).
template <int OUTM, int SKIPN, int SKIPM, int CLAMPK, int AUX, int SPLITK>
__global__ __launch_bounds__(256, 2) void gemm256x128_kernel(
    const unsigned short* __restrict__ A, const unsigned short* __restrict__ B,
    void* __restrict__ Cp, int M, int N, int K,
    long a_bstride, long b_bstride, long c_bstride, float scale,
    const int* __restrict__ vlp, int lognx,
    const float* __restrict__ auxf, unsigned short* __restrict__ auxo, int ngemm) {
  __shared__ unsigned short lds[2][128 * 64 + 64 * 64];  // [ring][A:8192 | B:4096]

  const int tid = threadIdx.x;

  if constexpr (AUX == 1) {  // queries cast backfill
    if ((int)blockIdx.x >= ngemm) {
      size_t i = ((size_t)((int)blockIdx.x - ngemm) * 256 + tid) * 8;
      float4 a = *(const float4*)(auxf + i);
      float4 b = *(const float4*)(auxf + i + 4);
      ushortx8 o;
      o[0] = f2bf(a.x); o[1] = f2bf(a.y); o[2] = f2bf(a.z); o[3] = f2bf(a.w);
      o[4] = f2bf(b.x); o[5] = f2bf(b.y); o[6] = f2bf(b.z); o[7] = f2bf(b.w);
      *(ushortx8*)(auxo + i) = o;
      return;
    }
  }

  const int wid = tid >> 6;
  const int lane = tid & 63;
  const int lane15 = lane & 15;
  const int lhalf = lane >> 4;

  // ---- 1-D grid decode: z inner, then (optional) sk, then x, y ----
  const int idx = (int)blockIdx.x;
  const int z = idx & 7;
  int rest = idx >> 3;
  int sk = 0;
  if constexpr (SPLITK) {
    sk = rest & 1;
    rest >>= 1;
  }
  const int nxm = (1 << lognx) - 1;
  const int xt = rest & nxm;
  const int yt = rest >> lognx;
  const int nt = (xt + 2 * z) & nxm;  // batch-rotated n-tile
  const int m0 = yt * 256;
  const int n0 = nt * 128;

  int vl = K;
  if constexpr (SKIPN || SKIPM || CLAMPK) vl = vlp[z];
  if constexpr (SKIPN) {
    if (n0 >= vl) return;
  }
  if constexpr (SKIPM) {
    if (m0 >= vl) return;
  }
  int kEnd = K;
  if constexpr (CLAMPK) {
    int ke = (vl + 63) & ~63;
    kEnd = ke < K ? ke : K;
  }
  const int nKt = kEnd >> 5;  // K-tiles of 32; even, >= 2

  int t0 = 0, t1 = nKt;
  bool split = false;
  if constexpr (SPLITK) {
    if (nKt >= 32) {  // split only long-K batches; nKt even -> equal halves
      split = true;
      const int h = nKt >> 1;
      if (sk) t0 = h; else t1 = h;
    } else if (sk) {
      return;  // short batch: sk=0 does full K with plain stores
    }
  }

  const unsigned short* Ab = A + (size_t)z * a_bstride;
  const unsigned short* Bb = B + (size_t)z * b_bstride;

  // ---- staging precompute: A 1024 chunks (4/thr), B 512 chunks (2/thr) ----
  // chunk blk: p=blk>>3 (rowpair), c=(blk&7)^(p&7): src row=2p+(c>>2),
  // src col=(c&3)*8, LDS dst=blk*16B (within operand region).
  int srA[4], scA[4], sdA[4];
#pragma unroll
  for (int j = 0; j < 4; ++j) {
    int blk = (wid * 4 + j) * 64 + lane;  // wave-uniform base + lane (gld_lds req)
    int p = blk >> 3;
    int c = (blk & 7) ^ (p & 7);
    srA[j] = m0 + 2 * p + (c >> 2);
    scA[j] = (c & 3) * 8;
    sdA[j] = blk * 8;
  }
  int srB[2], scB[2], sdB[2];
#pragma unroll
  for (int j = 0; j < 2; ++j) {
    int blk = (wid * 2 + j) * 64 + lane;
    int p = blk >> 3;
    int c = (blk & 7) ^ (p & 7);
    srB[j] = n0 + 2 * p + (c >> 2);
    scB[j] = (c & 3) * 8;
    sdB[j] = 8192 + blk * 8;
  }

  // ---- read precompute (wave 2M x 2N -> 128x64 each) ----
  const int om = (wid & 1) * 128;  // wave M origin in tile
  const int on = (wid >> 1) * 64;  // wave N origin in tile
  const int swz8 = ((((lane15 & 1) << 2) + lhalf) ^ ((lane15 >> 1) & 7)) << 3;
  const int aBase = ((om >> 1) + (lane15 >> 1)) * 64 + swz8;
  const int bBase = 8192 + ((on >> 1) + (lane15 >> 1)) * 64 + swz8;

  f32x4 acc[8][4];
#pragma unroll
  for (int f = 0; f < 8; ++f)
#pragma unroll
    for (int g = 0; g < 4; ++g) acc[f][g] = (f32x4){0.f, 0.f, 0.f, 0.f};

#define STAGE_TILE(T, S)                                                        \
  {                                                                             \
    const int kc_ = (T) * 32;                                                   \
    _Pragma("unroll")                                                           \
    for (int j = 0; j < 4; ++j)                                                 \
      gld_lds16(Ab + (size_t)srA[j] * K + (kc_ + scA[j]), &lds[S][sdA[j]]);     \
    _Pragma("unroll")                                                           \
    for (int j = 0; j < 2; ++j)                                                 \
      gld_lds16(Bb + (size_t)srB[j] * K + (kc_ + scB[j]), &lds[S][sdB[j]]);     \
  }

  // ---- prologue: stage first tile into slot 0 ----
  STAGE_TILE(t0, 0);
  asm volatile("s_waitcnt vmcnt(0)" ::: "memory");
  __builtin_amdgcn_s_barrier();

  for (int t = t0; t < t1; ++t) {
    const int cur = (t - t0) & 1;
    const unsigned short* lcur = &lds[cur][0];
    // issue next tile's staging first (vmem counter); lands under this tile's body
    if (t + 1 < t1) STAGE_TILE(t + 1, cur ^ 1);

    bf16x8 a[8], b[4];
#pragma unroll
    for (int f = 0; f < 8; ++f) a[f] = *(const bf16x8*)&lcur[aBase + f * 512];
#pragma unroll
    for (int g = 0; g < 4; ++g) b[g] = *(const bf16x8*)&lcur[bBase + g * 512];
    // UNPINNED: compiler emits fine-grained lgkmcnt between reads and MFMAs.
#pragma unroll
    for (int f = 0; f < 8; ++f)
#pragma unroll
      for (int g = 0; g < 4; ++g)
        acc[f][g] = __builtin_amdgcn_mfma_f32_16x16x32_bf16(a[f], b[g], acc[f][g], 0, 0, 0);
    asm volatile("s_waitcnt vmcnt(0)" ::: "memory");  // next tile resident (fence)
    __builtin_amdgcn_s_barrier();
  }
#undef STAGE_TILE

  // ---- epilogue: C/D layout col=lane&15, row=(lane>>4)*4+reg ----
  const size_t boffC = (size_t)z * c_bstride;
#pragma unroll
  for (int f = 0; f < 8; ++f) {
    int row = m0 + om + f * 16 + lhalf * 4;
#pragma unroll
    for (int g = 0; g < 4; ++g) {
      int col = n0 + on + g * 16 + lane15;
#pragma unroll
      for (int r = 0; r < 4; ++r) {
        float v = acc[f][g][r];
        if constexpr (OUTM == 0) {
          ((unsigned short*)Cp + boffC)[(size_t)(row + r) * N + col] = f2bf(v);
        } else if constexpr (OUTM == 1) {
          ((unsigned short*)Cp + boffC)[(size_t)(row + r) * N + col] = f2bf(v * scale);
        } else {
          float* op = (float*)Cp + boffC;
          if constexpr (SPLITK) {
            if (split) {
              __hip_atomic_fetch_add(&op[(size_t)(row + r) * N + col], v,
                                     __ATOMIC_RELAXED, __HIP_MEMORY_SCOPE_AGENT);
              continue;
            }
          }
          op[(size_t)(row + r) * N + col] = v;
        }
      }
    }
  }
}

// ========== fused transposeV + softmax + split-K zero-init ==========
// blocks [0,16384): valsT[b][v][s] = values[b][s][v] (bf16), s-tiles clamped to
//   round64(vl) (GEMM3 never reads beyond). decode idx = x + 32y + 2048z.
// blocks [16384,32768): row softmax with valid_len masking, in place on bf16
//   scores; cols [vl, round64(vl)) get exact 0 (GEMM3 CLAMPK read range).
// blocks [32768,34816): zero-init `out` for split-K batches (round64(vl) >= 1024,
//   matching GEMM3's nKt >= 32 split condition). Stream-ordered before GEMM3.
__global__ __launch_bounds__(256) void vtrans_softmax_zero_kernel(
    const float* __restrict__ vals, unsigned short* __restrict__ valsT,
    unsigned short* __restrict__ scores, const int* __restrict__ valid_lens,
    float* __restrict__ out) {
  __shared__ float smem[32 * 33];
  const int bb = (int)blockIdx.x;
  const int tid = threadIdx.x;

  if (bb >= 32768) {  // ---- zero-init region ----
    const int zb = bb - 32768;  // [0, 2048): 256 blocks x 32 KB per batch
    const int z = zb >> 8;
    if (((valid_lens[z] + 63) & ~63) >= 1024) {
      float* p = out + ((size_t)z << 21) + ((size_t)(zb & 255) << 13) + tid * 32;
      const f32x4 zer = {0.f, 0.f, 0.f, 0.f};
#pragma unroll
      for (int u = 0; u < 8; ++u) *(f32x4*)(p + u * 4) = zer;
    }
    return;
  }

  if (bb < 16384) {
    // ---- transpose+cast part: fp32 [2048][1024] -> bf16 [1024][2048] ----
    const int z = bb >> 11;
    const int r0 = ((bb >> 5) & 63) * 32;
    const int kEnd = (valid_lens[z] + 63) & ~63;
    if (r0 >= kEnd) return;
    const int c0 = (bb & 31) * 32;
    const int tx = tid & 31, ty = tid >> 5;  // (32,8)
    const float* inb = vals + (size_t)z * 2048 * 1024;
    unsigned short* outb = valsT + (size_t)z * 1024 * 2048;
#pragma unroll
    for (int k = 0; k < 4; ++k) {
      int r = ty + k * 8;
      smem[r * 33 + tx] = inb[(size_t)(r0 + r) * 1024 + c0 + tx];
    }
    __syncthreads();
#pragma unroll
    for (int k = 0; k < 4; ++k) {
      int c = ty + k * 8;
      outb[(size_t)(c0 + c) * 2048 + r0 + tx] = f2bf(smem[tx * 33 + c]);
    }
    return;
  }

  // ---- softmax part ----
  const int row = bb - 16384;
  const int b = row >> 11;  // LQ = 2048
  const int vl = valid_lens[b];
  const int kEnd = (vl + 63) & ~63;
  unsigned short* rp = scores + (size_t)row * LK_;
  const int wid = tid >> 6, lane = tid & 63;
  float* sred = smem;

  const int cb = tid * 8;
  const bool act = cb < kEnd;
  ushortx8 h = {};
  if (act) h = *(const ushortx8*)(rp + cb);
  float x[8];
#pragma unroll
  for (int t = 0; t < 8; ++t) x[t] = bf2f(h[t]);

  float m = -3.4e38f;
#pragma unroll
  for (int t = 0; t < 8; ++t)
    if (cb + t < vl) m = fmaxf(m, x[t]);
#pragma unroll
  for (int off = 32; off >= 1; off >>= 1) m = fmaxf(m, __shfl_xor(m, off));
  if (lane == 0) sred[wid] = m;
  __syncthreads();
  m = fmaxf(fmaxf(sred[0], sred[1]), fmaxf(sred[2], sred[3]));
  __syncthreads();

  float e[8];
  float s = 0.f;
#pragma unroll
  for (int t = 0; t < 8; ++t) {
    e[t] = (cb + t < vl) ? __expf(x[t] - m) : 0.f;
    s += e[t];
  }
#pragma unroll
  for (int off = 32; off >= 1; off >>= 1) s += __shfl_xor(s, off);
  if (lane == 0) sred[wid] = s;
  __syncthreads();
  s = sred[0] + sred[1] + sred[2] + sred[3];
  float inv = 1.f / s;

  if (act) {
    ushortx8 o;
#pragma unroll
    for (int t = 0; t < 8; ++t) o[t] = f2bf(e[t] * inv);
    *(ushortx8*)(rp + cb) = o;
  }
}

extern "C" void kernel_launch(void* const* d_in, const int* in_sizes, int n_in,
                              void* d_out, int out_size, void* d_ws, size_t ws_size,
                              hipStream_t stream) {
  const float* queries = (const float*)d_in[0];    // [8,2048,1024]
  const float* keys = (const float*)d_in[1];       // [8,2048,1024]
  const float* values = (const float*)d_in[2];     // [8,2048,1024]
  const int* valid_lens = (const int*)d_in[3];     // [8]
  const float* W_q = (const float*)d_in[4];        // [1024,1024]
  float* out = (float*)d_out;                      // [8,2048,1024] fp32

  // Re-association: scores = Q @ (K @ W^T)^T — project KEYS (maskable).
  // ws layout (ushort elems), total 81M = 162 MiB:
  //   q_bf    [0, 16M)      queries bf16
  //   scores  [16M, 48M)
  //   keysP   [48M, 64M)    K@W^T bf16
  //   w_bf    [64M, 65M)    W_q bf16 row-major (= B^T operand as-is)
  //   keys_bf [65M, 81M)    keys bf16; DEAD after GEMM1' -> valsT aliases it.
  unsigned short* ws = (unsigned short*)d_ws;
  const size_t M1 = (size_t)1024 * 1024;
  unsigned short* q_bf = ws;
  unsigned short* scores = ws + 16 * M1;
  unsigned short* keysP = ws + 48 * M1;
  unsigned short* w_bf = ws + 64 * M1;
  unsigned short* keys_bf = ws + 65 * M1;
  unsigned short* valsT = keys_bf;  // alias — keys_bf dead after GEMM1'

  // cast: keys (row-clamped to round256(vl)) + W_q. Queries cast fused into GEMM1'.
  cast_kw_kernel<<<dim3(8704), 256, 0, stream>>>(
      keys, keys_bf, W_q, w_bf, valid_lens);
  // GEMM1': keysP[b] = keys_bf[b] @ W_q^T -> bf16 [2048,1024]; skip m-tiles >= vl.
  // Blocks [0,512): GEMM (8y x 8x x 8z, z-inner; ~288 alive).
  // Blocks [512,8704): queries fp32->bf16 cast backfilling idle slots.
  gemm256x128_kernel<0, 0, 1, 0, 1, 0><<<dim3(512 + 8192), 256, 0, stream>>>(
      keys_bf, w_bf, keysP, 2048, 1024, 1024,
      (long)2048 * 1024, 0, (long)2048 * 1024, 1.f, valid_lens, 3,
      queries, q_bf, 512);
  // GEMM2': scores = q_bf @ keysP^T / 32 -> bf16; cull masked n-tiles.
  // grid: 8y x 16x x 8z, z-inner; ~544 alive.
  gemm256x128_kernel<1, 1, 0, 0, 0, 0><<<dim3(8 * 16 * 8), 256, 0, stream>>>(
      q_bf, keysP, scores, 2048, 2048, 1024,
      (long)2048 * 1024, (long)2048 * 1024, (long)2048 * 2048, 0.03125f, valid_lens, 4,
      nullptr, nullptr, 0);
  // fused: vtrans (clamped) + masked softmax + zero-init of out for split batches.
  vtrans_softmax_zero_kernel<<<dim3(34816), 256, 0, stream>>>(
      values, valsT, scores, valid_lens, out);
  // GEMM3: out = attn @ values (fp32); K clamped to round64(vl); split-K=2 for
  // long batches (atomic-add halves -> pole block 64 -> 32 K-tiles).
  // grid: 8y x 8x x 2sk x 8z (z inner, then sk), 1024 blocks.
  gemm256x128_kernel<2, 0, 0, 1, 0, 1><<<dim3(8 * 8 * 2 * 8), 256, 0, stream>>>(
      scores, valsT, out, 2048, 1024, 2048,
      (long)2048 * 2048, (long)1024 * 2048, (long)2048 * 1024, 1.f, valid_lens, 3,
      nullptr, nullptr, 0);
}